// Round 6
// baseline (656.009 us; speedup 1.0000x reference)
//
#include <hip/hip_runtime.h>

// Problem constants
#define NUM_Q 8
#define BN    8192      // B*N tokens
#define D     512
#define C     1024

// d_out layout (floats): [quantized_out | indices(as float) | losses]
#define QOUT_OFF 0
#define IDX_OFF  (BN * D)
#define LOSS_OFF (IDX_OFF + BN * NUM_Q)

// d_ws layout (bytes):
//   cbp: fragment-major packed f16 codebook, per layer q (1,048,576 f16 elems = 2MB):
//     elem offset = q*1048576 + colblock*16384 + kb*1024 + {hi:0|lo:512} + (c&15)*32 + k_in
//   e2: [NUM_Q*C] float at 16MB
#define CBP_OFF_B 0
#define E2_OFF_B  (NUM_Q * C * 1024 * 2)   // 16 MB

typedef _Float16 f16x8 __attribute__((ext_vector_type(8)));
typedef _Float16 f16x4 __attribute__((ext_vector_type(4)));
typedef float    f32x4 __attribute__((ext_vector_type(4)));

__device__ __forceinline__ unsigned fkey(float f) {
    unsigned u = __float_as_uint(f);
    return (u & 0x80000000u) ? ~u : (u | 0x80000000u);
}
__device__ __forceinline__ unsigned long long u64min(unsigned long long a, unsigned long long b) {
    return a < b ? a : b;
}
__device__ __forceinline__ unsigned long long shfl_xor_u64(unsigned long long v, int m) {
    int lo = __shfl_xor((int)(unsigned)v, m, 64);
    int hi = __shfl_xor((int)(unsigned)(v >> 32), m, 64);
    return ((unsigned long long)(unsigned)hi << 32) | (unsigned)lo;
}

// ---------------------------------------------------------------------------
// prep: per codebook row, split f32 -> f16 hi/lo into fragment-major layout,
// compute e2. One wave per row; also zero the loss outputs.
// ---------------------------------------------------------------------------
__global__ __launch_bounds__(256) void rvq_prep(const float* __restrict__ cbs,
                                                _Float16* __restrict__ cbp,
                                                float* __restrict__ e2ws,
                                                float* __restrict__ out) {
    const int row  = blockIdx.x * 4 + (threadIdx.x >> 6);
    const int lane = threadIdx.x & 63;
    const float* p = cbs + (size_t)row * D + lane * 8;
    float4 a = *(const float4*)p;
    float4 b = *(const float4*)(p + 4);
    float av[8] = {a.x, a.y, a.z, a.w, b.x, b.y, b.z, b.w};
    f16x8 h, l;
    float ss = 0.f;
#pragma unroll
    for (int i = 0; i < 8; ++i) {
        _Float16 hi = (_Float16)av[i];
        h[i] = hi;
        l[i] = (_Float16)(av[i] - (float)hi);
        ss += av[i] * av[i];
    }
    const int qq = row >> 10;
    const int c  = row & 1023;
    _Float16* dst = cbp + (size_t)qq * 1048576 + (c >> 4) * 16384
                  + (lane >> 2) * 1024 + (c & 15) * 32 + (lane & 3) * 8;
    *(f16x8*)dst         = h;
    *(f16x8*)(dst + 512) = l;
#pragma unroll
    for (int off = 32; off >= 1; off >>= 1) ss += __shfl_xor(ss, off, 64);
    if (lane == 0) e2ws[row] = ss;
    if (blockIdx.x == 0 && threadIdx.x < NUM_Q) out[LOSS_OFF + threadIdx.x] = 0.0f;
}

// ---------------------------------------------------------------------------
// fused persistent RVQ: 256 WGs x 1024 threads (16 waves) x 32 tokens.
// Each wave owns 64 codeword columns (4 colblocks); 4 waves/SIMD resident.
//
// OCCUPANCY/REGISTER CONTRACT: amdgpu_waves_per_eu(4,4) pins the allocator's
// occupancy TARGET to 4 waves/EU (= our structural 1 WG/CU), granting the
// 128-VGPR budget. __launch_bounds__(1024,4) only set a MINIMUM of 4 — the
// allocator still targeted 8 waves/EU (LDS would allow 2 blocks/CU) and
// budgeted 64 VGPRs, spilling the prefetch buffers to scratch (rounds 3-5:
// VGPR_Count=64, WRITE_SIZE 86MB vs 33MB expected, MfmaUtil stuck at 13%).
//
// B prefetch: 4 statically-indexed single-colblock register buffers, each
// reloaded for kb+1 right after its 6 MFMAs at kb (issue-to-use = 18 MFMAs).
// Per-kb raw s_barrier paces the 16 waves in lockstep (keeps the layer's
// 2MB codebook L2-resident) WITHOUT the vmcnt(0) drain __syncthreads emits.
// ---------------------------------------------------------------------------
__global__
__attribute__((amdgpu_flat_work_group_size(1024, 1024), amdgpu_waves_per_eu(4, 4)))
void rvq_fused(
    const float* __restrict__ x, const float* __restrict__ cbs,
    const _Float16* __restrict__ cbp, const float* __restrict__ e2ws,
    float* __restrict__ out)
{
    // A_hi [0,32KB) | A_lo [32KB,64KB); argmin scratch aliases (barrier-guarded)
    __shared__ __align__(16) unsigned char smem[65536];

    const int tid  = threadIdx.x;
    const int lane = tid & 63;
    const int wv   = tid >> 6;     // wave 0..15 -> cols [wv*64, wv*64+64)
    const int lm   = lane & 15;
    const int lq   = lane >> 4;
    const int tl   = tid >> 5;     // token 0..31 within WG
    const int g    = tid & 31;     // owns k = g*4 + 128*j, j=0..3 (float4 granules)
    const int tok0 = blockIdx.x * 32;

    // swizzled A byte address: row*1024 + 2*k, XOR spreads rows over bank slots
    auto aab = [](int row, int kbyte) -> unsigned {
        return (((unsigned)row << 10) + (unsigned)kbyte) ^ (unsigned)((row & 7) << 4);
    };

    // residual in registers: 16 f32/thread as 4x float4
    float4 r4[4];
    {
        const float* xr = x + (size_t)(tok0 + tl) * D + g * 4;
#pragma unroll
        for (int j = 0; j < 4; ++j) r4[j] = *(const float4*)(xr + j * 128);
    }

    unsigned long long* red = (unsigned long long*)smem;   // [16][32] after barrier

    // wave's B base: first colblock (wv*4); lane's fragment slot (row lm, k lq*8)
    const _Float16* bq = cbp + (size_t)(wv * 4) * 16384 + lm * 32 + lq * 8;

    // 4 single-colblock register buffers (static index = colblock-in-wave)
    f16x8 pbh[4], pbl[4];

    // prologue: q=0, kb=0, all 4 colblocks
#pragma unroll
    for (int c = 0; c < 4; ++c) {
        const _Float16* p = bq + c * 16384;
        pbh[c] = *(const f16x8*)p;
        pbl[c] = *(const f16x8*)(p + 512);
    }

    for (int q = 0; q < NUM_Q; ++q) {
        // ---- build A (f16 hi/lo, swizzled) from residual regs ----
#pragma unroll
        for (int j = 0; j < 4; ++j) {
            float4 v = r4[j];
            f16x4 h, l;
            h[0] = (_Float16)v.x; l[0] = (_Float16)(v.x - (float)h[0]);
            h[1] = (_Float16)v.y; l[1] = (_Float16)(v.y - (float)h[1]);
            h[2] = (_Float16)v.z; l[2] = (_Float16)(v.z - (float)h[2]);
            h[3] = (_Float16)v.w; l[3] = (_Float16)(v.w - (float)h[3]);
            unsigned b = aab(tl, g * 8 + j * 256);
            *(f16x4*)(smem + b)         = h;
            *(f16x4*)(smem + 32768 + b) = l;
        }
        __syncthreads();

        f32x4 acc[2][4];
#pragma unroll
        for (int mt = 0; mt < 2; ++mt)
#pragma unroll
            for (int nt = 0; nt < 4; ++nt)
                acc[mt][nt] = (f32x4){0.f, 0.f, 0.f, 0.f};

        const int qb = q * 1048576;

        // ---- K loop: per kb {4 A ds_reads | 4x(6 MFMA + refill)} + pacing barrier
        for (int kb = 0; kb < 16; ++kb) {
            unsigned b0 = aab(lm,      kb * 64 + lq * 16);
            unsigned b1 = aab(16 + lm, kb * 64 + lq * 16);
            f16x8 ah0 = *(const f16x8*)(smem + b0);
            f16x8 ah1 = *(const f16x8*)(smem + b1);
            f16x8 al0 = *(const f16x8*)(smem + 32768 + b0);
            f16x8 al1 = *(const f16x8*)(smem + 32768 + b1);

            // refill offset: next kb, or next layer's kb0 at kb==15
            // (q==7 tail reads e2/pad bytes inside the 256MB ws — harmless)
            const int roff = (kb < 15) ? (qb + (kb + 1) * 1024) : (qb + 1048576);

            __builtin_amdgcn_s_setprio(1);
#pragma unroll
            for (int c = 0; c < 4; ++c) {
                // per-accumulator order hh, hl, lh (bit-matches prior rounds)
                acc[0][c] = __builtin_amdgcn_mfma_f32_16x16x32_f16(ah0, pbh[c], acc[0][c], 0, 0, 0);
                acc[1][c] = __builtin_amdgcn_mfma_f32_16x16x32_f16(ah1, pbh[c], acc[1][c], 0, 0, 0);
                acc[0][c] = __builtin_amdgcn_mfma_f32_16x16x32_f16(ah0, pbl[c], acc[0][c], 0, 0, 0);
                acc[1][c] = __builtin_amdgcn_mfma_f32_16x16x32_f16(ah1, pbl[c], acc[1][c], 0, 0, 0);
                acc[0][c] = __builtin_amdgcn_mfma_f32_16x16x32_f16(al0, pbh[c], acc[0][c], 0, 0, 0);
                acc[1][c] = __builtin_amdgcn_mfma_f32_16x16x32_f16(al1, pbh[c], acc[1][c], 0, 0, 0);
                // reload this colblock for next kb (used after 3 more colblocks)
                const _Float16* p = bq + roff + c * 16384;
                pbh[c] = *(const f16x8*)p;
                pbl[c] = *(const f16x8*)(p + 512);
            }
            __builtin_amdgcn_s_setprio(0);
            __builtin_amdgcn_s_barrier();   // pacing only: A is read-only here
        }
        __syncthreads();   // all waves done with A; red may alias it now

        // ---- scores + per-token argmin over this wave's 64 cols ----
        const float* e2q = e2ws + q * C;
        float e2v[4];
#pragma unroll
        for (int nt = 0; nt < 4; ++nt) e2v[nt] = e2q[wv * 64 + nt * 16 + lm];

        unsigned long long best[2][4];
#pragma unroll
        for (int mt = 0; mt < 2; ++mt)
#pragma unroll
            for (int r = 0; r < 4; ++r) best[mt][r] = ~0ull;

#pragma unroll
        for (int mt = 0; mt < 2; ++mt)
#pragma unroll
            for (int nt = 0; nt < 4; ++nt) {
                unsigned col = (unsigned)(wv * 64 + nt * 16 + lm);
#pragma unroll
                for (int r = 0; r < 4; ++r) {
                    float s = e2v[nt] - 2.0f * acc[mt][nt][r];
                    unsigned long long p = ((unsigned long long)fkey(s) << 32) | col;
                    best[mt][r] = u64min(best[mt][r], p);
                }
            }
#pragma unroll
        for (int mt = 0; mt < 2; ++mt)
#pragma unroll
            for (int r = 0; r < 4; ++r) {
#pragma unroll
                for (int off = 1; off < 16; off <<= 1)
                    best[mt][r] = u64min(best[mt][r], shfl_xor_u64(best[mt][r], off));
                if (lm == 0) red[wv * 32 + mt * 16 + lq * 4 + r] = best[mt][r];
            }
        __syncthreads();
        if (tid < 32) {
            unsigned long long p = red[tid];
#pragma unroll
            for (int w = 1; w < 16; ++w) p = u64min(p, red[w * 32 + tid]);
            red[tid] = p;
        }
        __syncthreads();
        const unsigned bidx = (unsigned)(red[tl] & 0xffffffffull);

        // ---- update residual in regs, emit index, accumulate loss ----
        const float* cw = cbs + ((size_t)q * C + bidx) * D + g * 4;
        float ss = 0.f;
#pragma unroll
        for (int j = 0; j < 4; ++j) {
            float4 c = *(const float4*)(cw + j * 128);
            float4 v = r4[j];
            v.x -= c.x; v.y -= c.y; v.z -= c.z; v.w -= c.w;
            r4[j] = v;
            ss += v.x * v.x + v.y * v.y + v.z * v.z + v.w * v.w;
        }
        if (g == 0) out[IDX_OFF + (size_t)(tok0 + tl) * NUM_Q + q] = (float)bidx;
        // 64-lane reduce sums both tokens held by this wave (loss is a global sum)
#pragma unroll
        for (int off = 32; off >= 1; off >>= 1) ss += __shfl_xor(ss, off, 64);
        if (lane == 0) atomicAdd(out + LOSS_OFF + q, ss * (1.0f / ((float)BN * (float)D)));
        __syncthreads();   // protect red/A before next layer's build
    }

    // ---- finalize: quantized_out = x - residual_final ----
    {
        const float* xr = x + (size_t)(tok0 + tl) * D + g * 4;
        float* qo = out + QOUT_OFF + (size_t)(tok0 + tl) * D + g * 4;
#pragma unroll
        for (int j = 0; j < 4; ++j) {
            float4 xv = *(const float4*)(xr + j * 128);
            float4 v  = r4[j];
            *(float4*)(qo + j * 128) =
                make_float4(xv.x - v.x, xv.y - v.y, xv.z - v.z, xv.w - v.w);
        }
    }
}

extern "C" void kernel_launch(void* const* d_in, const int* in_sizes, int n_in,
                              void* d_out, int out_size, void* d_ws, size_t ws_size,
                              hipStream_t stream) {
    const float* x   = (const float*)d_in[0];
    const float* cbs = (const float*)d_in[1];
    float* out = (float*)d_out;
    _Float16* cbp = (_Float16*)((char*)d_ws + CBP_OFF_B);
    float* e2ws   = (float*)((char*)d_ws + E2_OFF_B);

    hipLaunchKernelGGL(rvq_prep,  dim3(NUM_Q * C / 4), dim3(256),  0, stream, cbs, cbp, e2ws, out);
    hipLaunchKernelGGL(rvq_fused, dim3(BN / 32),       dim3(1024), 0, stream, x, cbs, cbp, e2ws, out);
}

// Round 7
// 516.586 us; speedup vs baseline: 1.2699x; 1.2699x over previous
//
#include <hip/hip_runtime.h>

// Problem constants
#define NUM_Q 8
#define BN    8192      // B*N tokens
#define D     512
#define C     1024

// d_out layout (floats): [quantized_out | indices(as float) | losses]
#define QOUT_OFF 0
#define IDX_OFF  (BN * D)
#define LOSS_OFF (IDX_OFF + BN * NUM_Q)

// d_ws layout (bytes):
//   cbp: fragment-major packed f16 codebook, per layer q (1,048,576 f16 elems = 2MB):
//     elem offset = q*1048576 + colblock*16384 + kb*1024 + {hi:0|lo:512} + (c&15)*32 + k_in
//   e2: [NUM_Q*C] float at 16MB
#define CBP_OFF_B 0
#define E2_OFF_B  (NUM_Q * C * 1024 * 2)   // 16 MB

typedef _Float16 f16x8 __attribute__((ext_vector_type(8)));
typedef _Float16 f16x4 __attribute__((ext_vector_type(4)));
typedef float    f32x4 __attribute__((ext_vector_type(4)));

__device__ __forceinline__ unsigned fkey(float f) {
    unsigned u = __float_as_uint(f);
    return (u & 0x80000000u) ? ~u : (u | 0x80000000u);
}
__device__ __forceinline__ unsigned long long u64min(unsigned long long a, unsigned long long b) {
    return a < b ? a : b;
}
__device__ __forceinline__ unsigned long long shfl_xor_u64(unsigned long long v, int m) {
    int lo = __shfl_xor((int)(unsigned)v, m, 64);
    int hi = __shfl_xor((int)(unsigned)(v >> 32), m, 64);
    return ((unsigned long long)(unsigned)hi << 32) | (unsigned)lo;
}

// ---------------------------------------------------------------------------
// prep: per codebook row, split f32 -> f16 hi/lo into fragment-major layout,
// compute e2. One wave per row; also zero the loss outputs.
// ---------------------------------------------------------------------------
__global__ __launch_bounds__(256) void rvq_prep(const float* __restrict__ cbs,
                                                _Float16* __restrict__ cbp,
                                                float* __restrict__ e2ws,
                                                float* __restrict__ out) {
    const int row  = blockIdx.x * 4 + (threadIdx.x >> 6);
    const int lane = threadIdx.x & 63;
    const float* p = cbs + (size_t)row * D + lane * 8;
    float4 a = *(const float4*)p;
    float4 b = *(const float4*)(p + 4);
    float av[8] = {a.x, a.y, a.z, a.w, b.x, b.y, b.z, b.w};
    f16x8 h, l;
    float ss = 0.f;
#pragma unroll
    for (int i = 0; i < 8; ++i) {
        _Float16 hi = (_Float16)av[i];
        h[i] = hi;
        l[i] = (_Float16)(av[i] - (float)hi);
        ss += av[i] * av[i];
    }
    const int qq = row >> 10;
    const int c  = row & 1023;
    _Float16* dst = cbp + (size_t)qq * 1048576 + (c >> 4) * 16384
                  + (lane >> 2) * 1024 + (c & 15) * 32 + (lane & 3) * 8;
    *(f16x8*)dst         = h;
    *(f16x8*)(dst + 512) = l;
#pragma unroll
    for (int off = 32; off >= 1; off >>= 1) ss += __shfl_xor(ss, off, 64);
    if (lane == 0) e2ws[row] = ss;
    if (blockIdx.x == 0 && threadIdx.x < NUM_Q) out[LOSS_OFF + threadIdx.x] = 0.0f;
}

// ---------------------------------------------------------------------------
// fused persistent RVQ: 256 WGs x 512 threads (8 waves) x 32 tokens.
// REGISTER REGIME: this exact shape (512 thr + 64KB LDS) is the one the
// allocator gives a 128-VGPR budget (round 2: VGPR=128, WRITE clean).
// 1024-thread WGs were pinned at 64 VGPRs and spilled the B pipeline to
// scratch in rounds 3-6 (WRITE_SIZE 86MB, MfmaUtil 13%) — abandoned.
//
// Each wave owns 128 codeword columns (8 colblocks), processed in 2 CHUNKS
// of 4 colblocks (two K-passes over the LDS-resident A; B still read once).
// Chunking frees registers for a 4-buffer ROTATING B prefetch: pb[c] is
// refilled right after its 6 MFMAs and used next kb -> issue-to-use = 18
// MFMAs (~3x round 2's cover). No barriers inside/between chunks; kb=15 of
// chunk 1 prefetches chunk 2, of chunk 2 prefetches the next layer (covers
// the argmin/update epilogue). u64min folding is order-independent and the
// per-accumulator MFMA order (hh,hl,lh) is preserved -> outputs identical.
// ---------------------------------------------------------------------------
__global__ __launch_bounds__(512, 2) void rvq_fused(
    const float* __restrict__ x, const float* __restrict__ cbs,
    const _Float16* __restrict__ cbp, const float* __restrict__ e2ws,
    float* __restrict__ out)
{
    // A_hi [0,32KB) | A_lo [32KB,64KB); argmin scratch aliases (barrier-guarded)
    __shared__ __align__(16) unsigned char smem[65536];

    const int tid  = threadIdx.x;
    const int lane = tid & 63;
    const int wv   = tid >> 6;     // wave 0..7 -> cols [wv*128, wv*128+128)
    const int lm   = lane & 15;
    const int lq   = lane >> 4;
    const int tl   = tid >> 4;     // token 0..31 within WG
    const int g    = tid & 15;     // owns k = g*4 + 64*j, j=0..7 (float4 granules)
    const int tok0 = blockIdx.x * 32;

    // swizzled A byte address: row*1024 + 2*k, XOR spreads rows over bank slots
    auto aab = [](int row, int kbyte) -> unsigned {
        return (((unsigned)row << 10) + (unsigned)kbyte) ^ (unsigned)((row & 7) << 4);
    };

    // residual in registers: 32 f32/thread as 8x float4
    float4 r4[8];
    {
        const float* xr = x + (size_t)(tok0 + tl) * D + g * 4;
#pragma unroll
        for (int j = 0; j < 8; ++j) r4[j] = *(const float4*)(xr + j * 64);
    }

    unsigned long long* red = (unsigned long long*)smem;   // [8][32] after barrier

    // wave's B base: first colblock (wv*8); lane's fragment slot (row lm, k lq*8)
    const _Float16* bq = cbp + (size_t)(wv * 8) * 16384 + lm * 32 + lq * 8;

    // 4 rotating single-colblock register buffers (static index c)
    f16x8 pbh[4], pbl[4];

    // prologue: q=0, chunk 0, kb=0
#pragma unroll
    for (int c = 0; c < 4; ++c) {
        const _Float16* p = bq + c * 16384;
        pbh[c] = *(const f16x8*)p;
        pbl[c] = *(const f16x8*)(p + 512);
    }

    for (int q = 0; q < NUM_Q; ++q) {
        // ---- build A (f16 hi/lo, swizzled) from residual regs ----
#pragma unroll
        for (int j = 0; j < 8; ++j) {
            float4 v = r4[j];
            f16x4 h, l;
            h[0] = (_Float16)v.x; l[0] = (_Float16)(v.x - (float)h[0]);
            h[1] = (_Float16)v.y; l[1] = (_Float16)(v.y - (float)h[1]);
            h[2] = (_Float16)v.z; l[2] = (_Float16)(v.z - (float)h[2]);
            h[3] = (_Float16)v.w; l[3] = (_Float16)(v.w - (float)h[3]);
            unsigned b = aab(tl, (g * 4 + j * 64) * 2);
            *(f16x4*)(smem + b)         = h;
            *(f16x4*)(smem + 32768 + b) = l;
        }
        __syncthreads();

        const int qb = q * 1048576;
        const float* e2q = e2ws + q * C;

        unsigned long long best[2][4];
#pragma unroll
        for (int mt = 0; mt < 2; ++mt)
#pragma unroll
            for (int r = 0; r < 4; ++r) best[mt][r] = ~0ull;

        // ---- two column-chunks of 4 colblocks each ----
#pragma unroll
        for (int ch = 0; ch < 2; ++ch) {
            f32x4 acc[2][4];
#pragma unroll
            for (int mt = 0; mt < 2; ++mt)
#pragma unroll
                for (int nt = 0; nt < 4; ++nt)
                    acc[mt][nt] = (f32x4){0.f, 0.f, 0.f, 0.f};

#pragma unroll
            for (int kb = 0; kb < 16; ++kb) {
                unsigned b0 = aab(lm,      kb * 64 + lq * 16);
                unsigned b1 = aab(16 + lm, kb * 64 + lq * 16);
                f16x8 ah0 = *(const f16x8*)(smem + b0);
                f16x8 ah1 = *(const f16x8*)(smem + b1);
                f16x8 al0 = *(const f16x8*)(smem + 32768 + b0);
                f16x8 al1 = *(const f16x8*)(smem + 32768 + b1);

#pragma unroll
                for (int c = 0; c < 4; ++c) {
                    // per-accumulator order hh, hl, lh (bit-matches prior rounds)
                    acc[0][c] = __builtin_amdgcn_mfma_f32_16x16x32_f16(ah0, pbh[c], acc[0][c], 0, 0, 0);
                    acc[1][c] = __builtin_amdgcn_mfma_f32_16x16x32_f16(ah1, pbh[c], acc[1][c], 0, 0, 0);
                    acc[0][c] = __builtin_amdgcn_mfma_f32_16x16x32_f16(ah0, pbl[c], acc[0][c], 0, 0, 0);
                    acc[1][c] = __builtin_amdgcn_mfma_f32_16x16x32_f16(ah1, pbl[c], acc[1][c], 0, 0, 0);
                    acc[0][c] = __builtin_amdgcn_mfma_f32_16x16x32_f16(al0, pbh[c], acc[0][c], 0, 0, 0);
                    acc[1][c] = __builtin_amdgcn_mfma_f32_16x16x32_f16(al1, pbh[c], acc[1][c], 0, 0, 0);
                    // rotate: refill this buffer for the NEXT (ch,kb) position
                    // (used 18 MFMAs from now). q==7/ch==1 tail reads ws pad.
                    const _Float16* p =
                        (kb < 15) ? (bq + qb + (ch * 4 + c) * 16384 + (kb + 1) * 1024)
                      : (ch == 0) ? (bq + qb + (4 + c) * 16384)
                                  : (bq + qb + 1048576 + c * 16384);
                    pbh[c] = *(const f16x8*)p;
                    pbl[c] = *(const f16x8*)(p + 512);
                }
            }

            // ---- fold this chunk's scores into the running argmin ----
#pragma unroll
            for (int c = 0; c < 4; ++c) {
                const int nt = ch * 4 + c;
                const float e2v = e2q[wv * 128 + nt * 16 + lm];
                const unsigned col = (unsigned)(wv * 128 + nt * 16 + lm);
#pragma unroll
                for (int mt = 0; mt < 2; ++mt)
#pragma unroll
                    for (int r = 0; r < 4; ++r) {
                        float s = e2v - 2.0f * acc[mt][c][r];
                        unsigned long long pk = ((unsigned long long)fkey(s) << 32) | col;
                        best[mt][r] = u64min(best[mt][r], pk);
                    }
            }
        }
        __syncthreads();   // all waves done reading A; red may alias it now

        // ---- per-token argmin reduce ----
#pragma unroll
        for (int mt = 0; mt < 2; ++mt)
#pragma unroll
            for (int r = 0; r < 4; ++r) {
#pragma unroll
                for (int off = 1; off < 16; off <<= 1)
                    best[mt][r] = u64min(best[mt][r], shfl_xor_u64(best[mt][r], off));
                if (lm == 0) red[wv * 32 + mt * 16 + lq * 4 + r] = best[mt][r];
            }
        __syncthreads();
        if (tid < 32) {
            unsigned long long p = red[tid];
#pragma unroll
            for (int w = 1; w < 8; ++w) p = u64min(p, red[w * 32 + tid]);
            red[tid] = p;
        }
        __syncthreads();
        const unsigned bidx = (unsigned)(red[tl] & 0xffffffffull);

        // ---- update residual in regs, emit index, accumulate loss ----
        const float* cw = cbs + ((size_t)q * C + bidx) * D + g * 4;
        float ss = 0.f;
#pragma unroll
        for (int j = 0; j < 8; ++j) {
            float4 c = *(const float4*)(cw + j * 64);
            float4 v = r4[j];
            v.x -= c.x; v.y -= c.y; v.z -= c.z; v.w -= c.w;
            r4[j] = v;
            ss += v.x * v.x + v.y * v.y + v.z * v.z + v.w * v.w;
        }
        if (g == 0) out[IDX_OFF + (size_t)(tok0 + tl) * NUM_Q + q] = (float)bidx;
        // 64-lane reduce sums the 4 tokens held by this wave (loss is global)
#pragma unroll
        for (int off = 32; off >= 1; off >>= 1) ss += __shfl_xor(ss, off, 64);
        if (lane == 0) atomicAdd(out + LOSS_OFF + q, ss * (1.0f / ((float)BN * (float)D)));
        __syncthreads();   // protect red/A before next layer's build
    }

    // ---- finalize: quantized_out = x - residual_final ----
    {
        const float* xr = x + (size_t)(tok0 + tl) * D + g * 4;
        float* qo = out + QOUT_OFF + (size_t)(tok0 + tl) * D + g * 4;
#pragma unroll
        for (int j = 0; j < 8; ++j) {
            float4 xv = *(const float4*)(xr + j * 64);
            float4 v  = r4[j];
            *(float4*)(qo + j * 64) =
                make_float4(xv.x - v.x, xv.y - v.y, xv.z - v.z, xv.w - v.w);
        }
    }
}

extern "C" void kernel_launch(void* const* d_in, const int* in_sizes, int n_in,
                              void* d_out, int out_size, void* d_ws, size_t ws_size,
                              hipStream_t stream) {
    const float* x   = (const float*)d_in[0];
    const float* cbs = (const float*)d_in[1];
    float* out = (float*)d_out;
    _Float16* cbp = (_Float16*)((char*)d_ws + CBP_OFF_B);
    float* e2ws   = (float*)((char*)d_ws + E2_OFF_B);

    hipLaunchKernelGGL(rvq_prep,  dim3(NUM_Q * C / 4), dim3(256), 0, stream, cbs, cbp, e2ws, out);
    hipLaunchKernelGGL(rvq_fused, dim3(BN / 32),       dim3(512), 0, stream, x, cbs, cbp, e2ws, out);
}

// Round 8
// 510.435 us; speedup vs baseline: 1.2852x; 1.0120x over previous
//
#include <hip/hip_runtime.h>

// Problem constants
#define NUM_Q 8
#define BN    8192      // B*N tokens
#define D     512
#define C     1024

// d_out layout (floats): [quantized_out | indices(as float) | losses]
#define QOUT_OFF 0
#define IDX_OFF  (BN * D)
#define LOSS_OFF (IDX_OFF + BN * NUM_Q)

// d_ws layout (bytes):
//   cbp: fragment-major packed f16 codebook, per layer q (1,048,576 f16 elems = 2MB):
//     elem offset = q*1048576 + colblock*16384 + kb*1024 + {hi:0|lo:512} + (c&15)*32 + k_in
//   e2: [NUM_Q*C] float at 16MB
#define CBP_OFF_B 0
#define E2_OFF_B  (NUM_Q * C * 1024 * 2)   // 16 MB

typedef _Float16 f16x8 __attribute__((ext_vector_type(8)));
typedef _Float16 f16x4 __attribute__((ext_vector_type(4)));
typedef float    f32x4 __attribute__((ext_vector_type(4)));

__device__ __forceinline__ unsigned fkey(float f) {
    unsigned u = __float_as_uint(f);
    return (u & 0x80000000u) ? ~u : (u | 0x80000000u);
}
__device__ __forceinline__ unsigned long long u64min(unsigned long long a, unsigned long long b) {
    return a < b ? a : b;
}
__device__ __forceinline__ unsigned long long shfl_xor_u64(unsigned long long v, int m) {
    int lo = __shfl_xor((int)(unsigned)v, m, 64);
    int hi = __shfl_xor((int)(unsigned)(v >> 32), m, 64);
    return ((unsigned long long)(unsigned)hi << 32) | (unsigned)lo;
}

// ---------------------------------------------------------------------------
// prep: per codebook row, split f32 -> f16 hi/lo into fragment-major layout,
// compute e2. One wave per row; also zero the loss outputs.
// ---------------------------------------------------------------------------
__global__ __launch_bounds__(256) void rvq_prep(const float* __restrict__ cbs,
                                                _Float16* __restrict__ cbp,
                                                float* __restrict__ e2ws,
                                                float* __restrict__ out) {
    const int row  = blockIdx.x * 4 + (threadIdx.x >> 6);
    const int lane = threadIdx.x & 63;
    const float* p = cbs + (size_t)row * D + lane * 8;
    float4 a = *(const float4*)p;
    float4 b = *(const float4*)(p + 4);
    float av[8] = {a.x, a.y, a.z, a.w, b.x, b.y, b.z, b.w};
    f16x8 h, l;
    float ss = 0.f;
#pragma unroll
    for (int i = 0; i < 8; ++i) {
        _Float16 hi = (_Float16)av[i];
        h[i] = hi;
        l[i] = (_Float16)(av[i] - (float)hi);
        ss += av[i] * av[i];
    }
    const int qq = row >> 10;
    const int c  = row & 1023;
    _Float16* dst = cbp + (size_t)qq * 1048576 + (c >> 4) * 16384
                  + (lane >> 2) * 1024 + (c & 15) * 32 + (lane & 3) * 8;
    *(f16x8*)dst         = h;
    *(f16x8*)(dst + 512) = l;
#pragma unroll
    for (int off = 32; off >= 1; off >>= 1) ss += __shfl_xor(ss, off, 64);
    if (lane == 0) e2ws[row] = ss;
    if (blockIdx.x == 0 && threadIdx.x < NUM_Q) out[LOSS_OFF + threadIdx.x] = 0.0f;
}

// ---------------------------------------------------------------------------
// fused persistent RVQ: 256 WGs x 512 threads (8 waves) x 32 tokens.
//
// REGISTER CONTRACT (round-8 fix): LDS is padded to 84KB so 2 WGs/CU is
// impossible (2x84 > 160KB). The allocator's occupancy target then drops to
// 2 waves/EU (= our structural reality: grid 256 = 1 WG/CU), unlocking the
// 256-VGPR budget that __launch_bounds__(512,2) permits. At 64KB LDS the
// allocator saw a hypothetical 2-WG/CU, targeted 4 waves/EU, and capped at
// 128 VGPRs (rounds 2/7) — too tight for a 2-kb-deep B pipeline.
//
// B prefetch: TWO-kb-deep rotation. Even/odd kb use separate register buffer
// sets (pbE/pbO, 4 colblocks each); the set used at kb is refilled for kb+2
// right after its MFMAs -> issue-to-use = 42 MFMAs (~815 SIMD-cyc of own-
// wave cover, ~2x loaded-L2 latency; round 7's 1-kb rotation gave ~470
// shared between 2 waves and stayed latency-bound at MfmaUtil 17%).
// Each wave owns 128 cols (8 colblocks) in 2 chunks of 4; B read exactly
// once; chunk/layer boundaries handled in the lookahead. Per-accumulator
// MFMA order (hh,hl,lh) and operand values unchanged -> outputs identical.
// ---------------------------------------------------------------------------
__global__ __launch_bounds__(512, 2) void rvq_fused(
    const float* __restrict__ x, const float* __restrict__ cbs,
    const _Float16* __restrict__ cbp, const float* __restrict__ e2ws,
    float* __restrict__ out)
{
    // A_hi [0,32KB) | A_lo [32KB,64KB) | pad to 84KB (occupancy fence).
    // argmin scratch aliases the A region (barrier-guarded).
    __shared__ __align__(16) unsigned char smem[86016];

    const int tid  = threadIdx.x;
    const int lane = tid & 63;
    const int wv   = tid >> 6;     // wave 0..7 -> cols [wv*128, wv*128+128)
    const int lm   = lane & 15;
    const int lq   = lane >> 4;
    const int tl   = tid >> 4;     // token 0..31 within WG
    const int g    = tid & 15;     // owns k = g*4 + 64*j, j=0..7 (float4 granules)
    const int tok0 = blockIdx.x * 32;

    // swizzled A byte address: row*1024 + 2*k, XOR spreads rows over bank slots
    auto aab = [](int row, int kbyte) -> unsigned {
        return (((unsigned)row << 10) + (unsigned)kbyte) ^ (unsigned)((row & 7) << 4);
    };

    // residual in registers: 32 f32/thread as 8x float4
    float4 r4[8];
    {
        const float* xr = x + (size_t)(tok0 + tl) * D + g * 4;
#pragma unroll
        for (int j = 0; j < 8; ++j) r4[j] = *(const float4*)(xr + j * 64);
    }

    unsigned long long* red = (unsigned long long*)smem;   // [8][32] after barrier

    // wave's B base: first colblock (wv*8); lane's fragment slot (row lm, k lq*8)
    const _Float16* bq = cbp + (size_t)(wv * 8) * 16384 + lm * 32 + lq * 8;

    // two-kb-deep rotating buffers: E = even kb, O = odd kb (all static-indexed)
    f16x8 pbhE[4], pblE[4], pbhO[4], pblO[4];

    // prologue: q=0, chunk 0, kb=0 (E) and kb=1 (O)
#pragma unroll
    for (int c = 0; c < 4; ++c) {
        const _Float16* p0 = bq + c * 16384;
        pbhE[c] = *(const f16x8*)p0;
        pblE[c] = *(const f16x8*)(p0 + 512);
        const _Float16* p1 = bq + c * 16384 + 1024;
        pbhO[c] = *(const f16x8*)p1;
        pblO[c] = *(const f16x8*)(p1 + 512);
    }

    for (int q = 0; q < NUM_Q; ++q) {
        // ---- build A (f16 hi/lo, swizzled) from residual regs ----
#pragma unroll
        for (int j = 0; j < 8; ++j) {
            float4 v = r4[j];
            f16x4 h, l;
            h[0] = (_Float16)v.x; l[0] = (_Float16)(v.x - (float)h[0]);
            h[1] = (_Float16)v.y; l[1] = (_Float16)(v.y - (float)h[1]);
            h[2] = (_Float16)v.z; l[2] = (_Float16)(v.z - (float)h[2]);
            h[3] = (_Float16)v.w; l[3] = (_Float16)(v.w - (float)h[3]);
            unsigned b = aab(tl, (g * 4 + j * 64) * 2);
            *(f16x4*)(smem + b)         = h;
            *(f16x4*)(smem + 32768 + b) = l;
        }
        __syncthreads();

        const int qb = q * 1048576;
        const float* e2q = e2ws + q * C;

        unsigned long long best[2][4];
#pragma unroll
        for (int mt = 0; mt < 2; ++mt)
#pragma unroll
            for (int r = 0; r < 4; ++r) best[mt][r] = ~0ull;

        // ---- two column-chunks of 4 colblocks each ----
#pragma unroll
        for (int ch = 0; ch < 2; ++ch) {
            f32x4 acc[2][4];
#pragma unroll
            for (int mt = 0; mt < 2; ++mt)
#pragma unroll
                for (int nt = 0; nt < 4; ++nt)
                    acc[mt][nt] = (f32x4){0.f, 0.f, 0.f, 0.f};

#pragma unroll
            for (int kb = 0; kb < 16; ++kb) {
                unsigned b0 = aab(lm,      kb * 64 + lq * 16);
                unsigned b1 = aab(16 + lm, kb * 64 + lq * 16);
                f16x8 ah0 = *(const f16x8*)(smem + b0);
                f16x8 ah1 = *(const f16x8*)(smem + b1);
                f16x8 al0 = *(const f16x8*)(smem + 32768 + b0);
                f16x8 al1 = *(const f16x8*)(smem + 32768 + b1);

                // lookahead base for position (ch,kb)+2; all kb/ch branches
                // fold at compile time (fully unrolled). q==7 tail reads ws
                // pad beyond cbp (within 256MB workspace) — values unused.
                const _Float16* tb;
                if (kb <= 13)      tb = bq + qb + (ch * 4) * 16384 + (kb + 2) * 1024;
                else if (ch == 0)  tb = bq + qb + 4 * 16384 + (kb - 14) * 1024;
                else               tb = bq + qb + 1048576 + (kb - 14) * 1024;

                if ((kb & 1) == 0) {
#pragma unroll
                    for (int c = 0; c < 4; ++c) {
                        // per-accumulator order hh, hl, lh (bit-matches prior rounds)
                        acc[0][c] = __builtin_amdgcn_mfma_f32_16x16x32_f16(ah0, pbhE[c], acc[0][c], 0, 0, 0);
                        acc[1][c] = __builtin_amdgcn_mfma_f32_16x16x32_f16(ah1, pbhE[c], acc[1][c], 0, 0, 0);
                        acc[0][c] = __builtin_amdgcn_mfma_f32_16x16x32_f16(ah0, pblE[c], acc[0][c], 0, 0, 0);
                        acc[1][c] = __builtin_amdgcn_mfma_f32_16x16x32_f16(ah1, pblE[c], acc[1][c], 0, 0, 0);
                        acc[0][c] = __builtin_amdgcn_mfma_f32_16x16x32_f16(al0, pbhE[c], acc[0][c], 0, 0, 0);
                        acc[1][c] = __builtin_amdgcn_mfma_f32_16x16x32_f16(al1, pbhE[c], acc[1][c], 0, 0, 0);
                        const _Float16* p = tb + c * 16384;
                        pbhE[c] = *(const f16x8*)p;
                        pblE[c] = *(const f16x8*)(p + 512);
                    }
                } else {
#pragma unroll
                    for (int c = 0; c < 4; ++c) {
                        acc[0][c] = __builtin_amdgcn_mfma_f32_16x16x32_f16(ah0, pbhO[c], acc[0][c], 0, 0, 0);
                        acc[1][c] = __builtin_amdgcn_mfma_f32_16x16x32_f16(ah1, pbhO[c], acc[1][c], 0, 0, 0);
                        acc[0][c] = __builtin_amdgcn_mfma_f32_16x16x32_f16(ah0, pblO[c], acc[0][c], 0, 0, 0);
                        acc[1][c] = __builtin_amdgcn_mfma_f32_16x16x32_f16(ah1, pblO[c], acc[1][c], 0, 0, 0);
                        acc[0][c] = __builtin_amdgcn_mfma_f32_16x16x32_f16(al0, pbhO[c], acc[0][c], 0, 0, 0);
                        acc[1][c] = __builtin_amdgcn_mfma_f32_16x16x32_f16(al1, pbhO[c], acc[1][c], 0, 0, 0);
                        const _Float16* p = tb + c * 16384;
                        pbhO[c] = *(const f16x8*)p;
                        pblO[c] = *(const f16x8*)(p + 512);
                    }
                }
            }

            // ---- fold this chunk's scores into the running argmin ----
#pragma unroll
            for (int c = 0; c < 4; ++c) {
                const int nt = ch * 4 + c;
                const float e2v = e2q[wv * 128 + nt * 16 + lm];
                const unsigned col = (unsigned)(wv * 128 + nt * 16 + lm);
#pragma unroll
                for (int mt = 0; mt < 2; ++mt)
#pragma unroll
                    for (int r = 0; r < 4; ++r) {
                        float s = e2v - 2.0f * acc[mt][c][r];
                        unsigned long long pk = ((unsigned long long)fkey(s) << 32) | col;
                        best[mt][r] = u64min(best[mt][r], pk);
                    }
            }
        }
        __syncthreads();   // all waves done reading A; red may alias it now

        // ---- per-token argmin reduce ----
#pragma unroll
        for (int mt = 0; mt < 2; ++mt)
#pragma unroll
            for (int r = 0; r < 4; ++r) {
#pragma unroll
                for (int off = 1; off < 16; off <<= 1)
                    best[mt][r] = u64min(best[mt][r], shfl_xor_u64(best[mt][r], off));
                if (lm == 0) red[wv * 32 + mt * 16 + lq * 4 + r] = best[mt][r];
            }
        __syncthreads();
        if (tid < 32) {
            unsigned long long p = red[tid];
#pragma unroll
            for (int w = 1; w < 8; ++w) p = u64min(p, red[w * 32 + tid]);
            red[tid] = p;
        }
        __syncthreads();
        const unsigned bidx = (unsigned)(red[tl] & 0xffffffffull);

        // ---- update residual in regs, emit index, accumulate loss ----
        const float* cw = cbs + ((size_t)q * C + bidx) * D + g * 4;
        float ss = 0.f;
#pragma unroll
        for (int j = 0; j < 8; ++j) {
            float4 c = *(const float4*)(cw + j * 64);
            float4 v = r4[j];
            v.x -= c.x; v.y -= c.y; v.z -= c.z; v.w -= c.w;
            r4[j] = v;
            ss += v.x * v.x + v.y * v.y + v.z * v.z + v.w * v.w;
        }
        if (g == 0) out[IDX_OFF + (size_t)(tok0 + tl) * NUM_Q + q] = (float)bidx;
        // 64-lane reduce sums the 4 tokens held by this wave (loss is global)
#pragma unroll
        for (int off = 32; off >= 1; off >>= 1) ss += __shfl_xor(ss, off, 64);
        if (lane == 0) atomicAdd(out + LOSS_OFF + q, ss * (1.0f / ((float)BN * (float)D)));
        __syncthreads();   // protect red/A before next layer's build
    }

    // ---- finalize: quantized_out = x - residual_final ----
    {
        const float* xr = x + (size_t)(tok0 + tl) * D + g * 4;
        float* qo = out + QOUT_OFF + (size_t)(tok0 + tl) * D + g * 4;
#pragma unroll
        for (int j = 0; j < 8; ++j) {
            float4 xv = *(const float4*)(xr + j * 64);
            float4 v  = r4[j];
            *(float4*)(qo + j * 64) =
                make_float4(xv.x - v.x, xv.y - v.y, xv.z - v.z, xv.w - v.w);
        }
    }
}

extern "C" void kernel_launch(void* const* d_in, const int* in_sizes, int n_in,
                              void* d_out, int out_size, void* d_ws, size_t ws_size,
                              hipStream_t stream) {
    const float* x   = (const float*)d_in[0];
    const float* cbs = (const float*)d_in[1];
    float* out = (float*)d_out;
    _Float16* cbp = (_Float16*)((char*)d_ws + CBP_OFF_B);
    float* e2ws   = (float*)((char*)d_ws + E2_OFF_B);

    hipLaunchKernelGGL(rvq_prep,  dim3(NUM_Q * C / 4), dim3(256), 0, stream, cbs, cbp, e2ws, out);
    hipLaunchKernelGGL(rvq_fused, dim3(BN / 32),       dim3(512), 0, stream, x, cbs, cbp, e2ws, out);
}